// Round 4
// baseline (283.003 us; speedup 1.0000x reference)
//
#include <hip/hip_runtime.h>

// MultiHeadModel routed MoE (E=8), round 4.
// Key change vs r3: NO weight pre-conversion. GEMMs read fp32 weights directly
// (reg-staged B: strided dword loads -> v_cvt_pk_bf16 -> transposing
// ds_write_b64 with XOR slot swizzle). Saves ~380 MB of HBM round-trip.
//   routing : single block
//   k_A     : a_build (perm-gathered fused rows -> bf16 Abuf) ∥ copy_vt
//   k_L1    : H{1,2} = relu(Abuf @ W1[e] + b1)   (both heads, direct fp32 B)
//   k_L2    : gene = H2 @ W2g[e] + b2  (scatter) ∥ immune dot

#define B_N 4096
#define DV  1024
#define DD  2048
#define HH  1024
#define GG  4096
#define EE  8
#define BM  128
#define MAXRB 40
#define PERM_N (MAXRB * BM)

typedef __bf16 bf16x8 __attribute__((ext_vector_type(8)));
typedef float f32x4 __attribute__((ext_vector_type(4)));
typedef unsigned short u16x4v __attribute__((ext_vector_type(4)));
typedef unsigned short u16x8v __attribute__((ext_vector_type(8)));

#define H_CNT 0
#define H_FIL 8
#define H_OFF 16
#define H_NRB 24
#define H_BLK 32

static __device__ __forceinline__ unsigned short f2bf(float f) {
  return __builtin_bit_cast(unsigned short, (__bf16)f);
}
static __device__ __forceinline__ float bf2f(unsigned short s) {
  return __builtin_bit_cast(float, (unsigned)s << 16);
}
static __device__ __forceinline__ void gload16(const void* g, void* l) {
  __builtin_amdgcn_global_load_lds(
      (const __attribute__((address_space(1))) unsigned int*)g,
      (__attribute__((address_space(3))) unsigned int*)l, 16, 0, 0);
}

// ---------------- routing: one block, 1024 threads ---------------------------
__global__ __launch_bounds__(1024) void routing(const int* __restrict__ organ,
                                                int* __restrict__ hdr,
                                                int* __restrict__ perm) {
  __shared__ int cnt[EE], fil[EE], off[EE];
  const int tid = threadIdx.x;
  if (tid < EE) { cnt[tid] = 0; fil[tid] = 0; }
  __syncthreads();
#pragma unroll
  for (int i = 0; i < 4; ++i) atomicAdd(&cnt[organ[tid + (i << 10)]], 1);
#pragma unroll
  for (int i = 0; i < 5; ++i) perm[tid + (i << 10)] = -1;
  __syncthreads();
  if (tid == 0) {
    int acc = 0;
    for (int e = 0; e < EE; ++e) {
      off[e] = acc;
      hdr[H_OFF + e] = acc;
      hdr[H_CNT + e] = cnt[e];
      int nb = (cnt[e] + BM - 1) >> 7;
      int rb0 = acc >> 7;
      for (int i = 0; i < nb; ++i) hdr[H_BLK + rb0 + i] = e;
      acc += nb << 7;
    }
    hdr[H_NRB] = acc >> 7;
  }
  __syncthreads();
#pragma unroll
  for (int i = 0; i < 4; ++i) {
    int b = tid + (i << 10);
    int e = organ[b];
    int slot = off[e] + atomicAdd(&fil[e], 1);
    perm[slot] = b;
  }
}

// ---------------- a_build: 4 rows per block ----------------------------------
static __device__ __forceinline__ void abuild_body(
    int bx, const float* __restrict__ vis, const float* __restrict__ txt,
    const int* __restrict__ hdr, const int* __restrict__ perm,
    unsigned short* __restrict__ Abuf) {
  const int nr = hdr[H_NRB] << 7;
  const int tid = threadIdx.x;
  const int c = tid << 3;
  const float* srcbase = (c < DV) ? vis : txt;
  const int cc = (c < DV) ? c : c - DV;
#pragma unroll
  for (int p = 0; p < 4; ++p) {
    int r = (bx << 2) + p;
    if (r >= nr) return;
    int smp = perm[r];
    u16x8v v;
    if (smp >= 0) {
      const float* src = srcbase + (size_t)smp * 1024 + cc;
      float4 a = *(const float4*)src, b = *(const float4*)(src + 4);
      v[0] = f2bf(a.x); v[1] = f2bf(a.y); v[2] = f2bf(a.z); v[3] = f2bf(a.w);
      v[4] = f2bf(b.x); v[5] = f2bf(b.y); v[6] = f2bf(b.z); v[7] = f2bf(b.w);
    } else {
#pragma unroll
      for (int i = 0; i < 8; ++i) v[i] = 0;
    }
    *(u16x8v*)&Abuf[(size_t)r * DD + c] = v;
  }
}

static __device__ __forceinline__ void copy_body(
    int bx, const float4* __restrict__ v, const float4* __restrict__ t,
    float4* __restrict__ ov, float4* __restrict__ ot) {
  const int n4 = B_N * DV / 4;
  for (int i = bx * 256 + (int)threadIdx.x; i < n4; i += 1024 * 256) {
    ov[i] = v[i];
    ot[i] = t[i];
  }
}

__global__ __launch_bounds__(256) void k_A(
    const float* __restrict__ vis, const float* __restrict__ txt,
    const int* __restrict__ hdr, const int* __restrict__ perm,
    unsigned short* __restrict__ Abuf, float4* __restrict__ ov,
    float4* __restrict__ ot) {
  int bx = blockIdx.x;
  if (bx < PERM_N / 4) { abuild_body(bx, vis, txt, hdr, perm, Abuf); return; }
  bx -= PERM_N / 4;
  copy_body(bx, (const float4*)vis, (const float4*)txt, ov, ot);
}

// ---------------- GEMM core: A bf16 via gload_lds, B fp32 reg-staged ---------
// smem (shorts): A0 @0, A1 @4096, B0 @8192, B1 @12288 (each 128 rows x 32)
// B LDS rows are [n][k] with 8B slot XOR-swizzle: slot' = slot ^ ((n^(n>>3))&7)
template <int KDIM, int NST>
static __device__ __forceinline__ void gemm_core(
    const unsigned short* __restrict__ Aseg,  // [128][KDIM] bf16 row-major
    const float* __restrict__ Bglob,          // [KDIM][NST] fp32 (col offset applied)
    unsigned short* smem, f32x4 (&acc)[4][4]) {
  const int tid = threadIdx.x;
  const int lane = tid & 63;
  const int wr = ((tid >> 6) >> 1) << 6, wc = ((tid >> 6) & 1) << 6;
  const int lr = lane & 15, lk = (lane >> 4) << 3;
  const int arow = tid >> 2, akq = (tid & 3) << 3;
  const int wbase = (tid & 192) << 3;
  const int bn = tid & 127, bkh = tid >> 7;        // B: n-row, k-half (0/1)
  const int bs3 = (bn ^ (bn >> 3)) & 7;            // write swizzle
  constexpr int NT = KDIM / 32;

  float bv[16];

  auto issueA = [&](int buf, int k0) {
    gload16(Aseg + (size_t)arow * KDIM + k0 + akq, smem + (buf << 12) + wbase);
    gload16(Aseg + (size_t)(64 + arow) * KDIM + k0 + akq,
            smem + (buf << 12) + 2048 + wbase);
  };
  auto issueB = [&](int k0) {
    const float* p = Bglob + (size_t)(k0 + (bkh << 4)) * NST + bn;
#pragma unroll
    for (int i = 0; i < 16; ++i) bv[i] = p[(size_t)i * NST];
  };
  auto writeB = [&](int buf) {
    unsigned short* row = smem + 8192 + (buf << 12) + (bn << 5);
#pragma unroll
    for (int j = 0; j < 4; ++j) {
      u16x4v w;
      w[0] = f2bf(bv[4 * j + 0]);
      w[1] = f2bf(bv[4 * j + 1]);
      w[2] = f2bf(bv[4 * j + 2]);
      w[3] = f2bf(bv[4 * j + 3]);
      *(u16x4v*)(row + ((((bkh << 2) + j) ^ bs3) << 2)) = w;
    }
  };

  issueA(0, 0);
  issueB(0);
  writeB(0);
  asm volatile("s_waitcnt vmcnt(0)" ::: "memory");
  __syncthreads();

#pragma unroll 2
  for (int kt = 0; kt < NT; ++kt) {
    const int cur = kt & 1;
    if (kt + 1 < NT) {
      issueA(cur ^ 1, (kt + 1) << 5);
      issueB((kt + 1) << 5);
    }
    bf16x8 af[4], bfr[4];
#pragma unroll
    for (int m = 0; m < 4; ++m)
      af[m] = *(const bf16x8*)&smem[(cur << 12) + (wr + m * 16 + lr) * 32 + lk];
#pragma unroll
    for (int n = 0; n < 4; ++n) {
      const int fr = wc + n * 16 + lr;
      const int s3 = (fr ^ (fr >> 3)) & 7;
      const unsigned short* row = smem + 8192 + (cur << 12) + (fr << 5);
      const int g = (lane >> 4) << 1;
      union { unsigned long long q[2]; bf16x8 v; } u;
      u.q[0] = *(const unsigned long long*)(row + ((g ^ s3) << 2));
      u.q[1] = *(const unsigned long long*)(row + (((g + 1) ^ s3) << 2));
      bfr[n] = u.v;
    }
#pragma unroll
    for (int m = 0; m < 4; ++m)
#pragma unroll
      for (int n = 0; n < 4; ++n)
        acc[m][n] = __builtin_amdgcn_mfma_f32_16x16x32_bf16(af[m], bfr[n], acc[m][n], 0, 0, 0);
    if (kt + 1 < NT) writeB(cur ^ 1);
    asm volatile("s_waitcnt vmcnt(0)" ::: "memory");
    __syncthreads();
  }
}

// ---------------- layer 1 ----------------------------------------------------
__global__ __launch_bounds__(256) void k_L1(
    const unsigned short* __restrict__ Abuf, const float* __restrict__ W1i,
    const float* __restrict__ W1g, const float* __restrict__ b1i,
    const float* __restrict__ b1g, const int* __restrict__ hdr,
    unsigned short* __restrict__ H1, unsigned short* __restrict__ H2) {
  __shared__ __align__(16) unsigned short smem[16384];
  const int bx = blockIdx.x;
  const int rb = bx >> 4;
  if (rb >= hdr[H_NRB]) return;
  const int sub = bx & 15, head = sub >> 3, cb = (sub & 7) << 7;
  const int e = hdr[H_BLK + rb];
  const float* Bglob = (head ? W1g : W1i) + (size_t)e * DD * HH + cb;
  const float* bias = (head ? b1g : b1i) + e * HH;
  unsigned short* Hout = head ? H2 : H1;
  const int tid = threadIdx.x;
  const int lane = tid & 63, wave = tid >> 6;
  const int wr = (wave >> 1) << 6, wc = (wave & 1) << 6;
  const int lr = lane & 15;

  f32x4 acc[4][4];
#pragma unroll
  for (int m = 0; m < 4; ++m)
#pragma unroll
    for (int n = 0; n < 4; ++n) acc[m][n] = (f32x4){0.f, 0.f, 0.f, 0.f};

  gemm_core<DD, HH>(Abuf + (size_t)rb * BM * DD, Bglob, smem, acc);

  // epilogue: bias+relu -> bf16 swizzled LDS -> coalesced store
  const int r0l = wr + ((lane >> 4) << 2);
#pragma unroll
  for (int n = 0; n < 4; ++n) {
    const int col = wc + n * 16 + lr;
    const float bv = bias[cb + col];
#pragma unroll
    for (int m = 0; m < 4; ++m)
#pragma unroll
      for (int v = 0; v < 4; ++v) {
        int row = r0l + m * 16 + v;
        float x = acc[m][n][v] + bv;
        x = x > 0.f ? x : 0.f;
        smem[((row << 7) + col) ^ ((row & 7) << 3)] = f2bf(x);
      }
  }
  __syncthreads();
#pragma unroll
  for (int c = 0; c < 8; ++c) {
    int q = c * 256 + tid;
    int row = q >> 4, ch = q & 15;
    int off = ((row << 7) + (ch << 3)) ^ ((row & 7) << 3);
    u16x8v val = *(const u16x8v*)&smem[off];
    *(u16x8v*)&Hout[(size_t)(rb * BM + row) * HH + cb + (ch << 3)] = val;
  }
}

// ---------------- immune dot -------------------------------------------------
static __device__ __forceinline__ void immune_body(
    int bx, const int* __restrict__ hdr, const int* __restrict__ perm,
    const unsigned short* __restrict__ H1, const float* __restrict__ W2,
    const float* __restrict__ b2, float* __restrict__ out) {
  const int nrb = hdr[H_NRB];
  const int r = bx * 4 + (threadIdx.x >> 6);
  if (r >= nrb * BM) return;
  const int b = perm[r];
  if (b < 0) return;
  const int e = hdr[H_BLK + (r >> 7)];
  const int lane = threadIdx.x & 63;
  const unsigned short* h = H1 + (size_t)r * HH + lane * 16;
  const float* w = W2 + (size_t)e * HH + lane * 16;
  float s = 0.f;
#pragma unroll
  for (int i = 0; i < 16; ++i) s += bf2f(h[i]) * w[i];
#pragma unroll
  for (int off = 32; off >= 1; off >>= 1) s += __shfl_xor(s, off, 64);
  if (lane == 0) out[b] = s + b2[e];
}

// ---------------- layer 2 (gene) ∥ immune ------------------------------------
#define G_L2 (MAXRB * 32)
__global__ __launch_bounds__(256) void k_L2(
    const unsigned short* __restrict__ H2buf, const float* __restrict__ W2g,
    const float* __restrict__ b2g, const int* __restrict__ hdr,
    const int* __restrict__ perm, float* __restrict__ outg,
    const unsigned short* __restrict__ H1, const float* __restrict__ W2i,
    const float* __restrict__ b2i, float* __restrict__ outi) {
  __shared__ __align__(16) unsigned short smem[16384];
  int bx = blockIdx.x;
  if (bx >= G_L2) {
    immune_body(bx - G_L2, hdr, perm, H1, W2i, b2i, outi);
    return;
  }
  const int rb = bx % MAXRB;
  const int cb = (bx / MAXRB) << 7;
  if (rb >= hdr[H_NRB]) return;
  const int e = hdr[H_BLK + rb];
  const float* Bglob = W2g + (size_t)e * HH * GG + cb;
  const int tid = threadIdx.x;
  const int lane = tid & 63, wave = tid >> 6;
  const int wr = (wave >> 1) << 6, wc = (wave & 1) << 6;
  const int lr = lane & 15;

  f32x4 acc[4][4];
#pragma unroll
  for (int m = 0; m < 4; ++m)
#pragma unroll
    for (int n = 0; n < 4; ++n) acc[m][n] = (f32x4){0.f, 0.f, 0.f, 0.f};

  gemm_core<HH, GG>(H2buf + (size_t)rb * BM * HH, Bglob, smem, acc);

  // epilogue: bias -> bf16 swizzled LDS -> fp32 scatter rows via perm
  const int r0l = wr + ((lane >> 4) << 2);
#pragma unroll
  for (int n = 0; n < 4; ++n) {
    const int col = wc + n * 16 + lr;
    const float bv = b2g[e * GG + cb + col];
#pragma unroll
    for (int m = 0; m < 4; ++m)
#pragma unroll
      for (int v = 0; v < 4; ++v) {
        int row = r0l + m * 16 + v;
        smem[((row << 7) + col) ^ ((row & 7) << 3)] = f2bf(acc[m][n][v] + bv);
      }
  }
  __syncthreads();
#pragma unroll
  for (int c = 0; c < 8; ++c) {
    int q = c * 256 + tid;
    int row = q >> 4, ch = q & 15;
    int sm = perm[rb * BM + row];
    if (sm < 0) continue;
    int off = ((row << 7) + (ch << 3)) ^ ((row & 7) << 3);
    u16x8v val = *(const u16x8v*)&smem[off];
    float4 f0, f1;
    f0.x = bf2f(val[0]); f0.y = bf2f(val[1]); f0.z = bf2f(val[2]); f0.w = bf2f(val[3]);
    f1.x = bf2f(val[4]); f1.y = bf2f(val[5]); f1.z = bf2f(val[6]); f1.w = bf2f(val[7]);
    float* dst = outg + (size_t)sm * GG + cb + (ch << 3);
    *(float4*)dst = f0;
    *(float4*)(dst + 4) = f1;
  }
}

// ================= host ======================================================
extern "C" void kernel_launch(void* const* d_in, const int* in_sizes, int n_in,
                              void* d_out, int out_size, void* d_ws, size_t ws_size,
                              hipStream_t stream) {
  (void)in_sizes; (void)n_in; (void)out_size; (void)ws_size;
  const float* vis = (const float*)d_in[0];
  const float* txt = (const float*)d_in[1];
  const float* W1i = (const float*)d_in[2];
  const float* b1i = (const float*)d_in[3];
  const float* W2i = (const float*)d_in[4];
  const float* b2i = (const float*)d_in[5];
  const float* W1g = (const float*)d_in[6];
  const float* b1g = (const float*)d_in[7];
  const float* W2g = (const float*)d_in[8];
  const float* b2g = (const float*)d_in[9];
  const int* organ = (const int*)d_in[10];

  float* out_imm = (float*)d_out;
  float* out_gene = out_imm + B_N;
  float* out_vis = out_gene + (size_t)B_N * GG;
  float* out_txt = out_vis + (size_t)B_N * DV;

  int* hdr = (int*)d_ws;
  int* perm = hdr + 128;

  const size_t OFF_ABUF = 32768;
  const size_t OFF_H1 = OFF_ABUF + (size_t)PERM_N * DD * 2;
  const size_t OFF_H2 = OFF_H1 + (size_t)PERM_N * HH * 2;
  unsigned short* Abuf = (unsigned short*)((char*)d_ws + OFF_ABUF);
  unsigned short* H1 = (unsigned short*)((char*)d_ws + OFF_H1);
  unsigned short* H2 = (unsigned short*)((char*)d_ws + OFF_H2);

  routing<<<1, 1024, 0, stream>>>(organ, hdr, perm);
  k_A<<<PERM_N / 4 + 1024, 256, 0, stream>>>(vis, txt, hdr, perm, Abuf,
                                             (float4*)out_vis, (float4*)out_txt);
  k_L1<<<MAXRB * 16, 256, 0, stream>>>(Abuf, W1i, W1g, b1i, b1g, hdr, H1, H2);
  k_L2<<<G_L2 + PERM_N / 4, 256, 0, stream>>>(H2, W2g, b2g, hdr, perm, out_gene,
                                              H1, W2i, b2i, out_imm);
}

// Round 7
// 259.042 us; speedup vs baseline: 1.0925x; 1.0925x over previous
//
#include <hip/hip_runtime.h>

// MultiHeadModel routed MoE (E=8), round 7.
// = round 6 with the K-offset UNIT BUG fixed: issueA/issueB take ELEMENT
// offsets; r5/r6 passed tile indices (t+1 instead of (t+1)*32) -> every
// K-tile after the first read the wrong K slice (deterministic absmax 6.8).
//   routing -> k_A(a_build) -> k_L1(GEMM both heads + copy_vt) -> k_L2(GEMM + immune)

#define B_N 4096
#define DV  1024
#define DD  2048
#define HH  1024
#define GG  4096
#define EE  8
#define BM  128
#define MAXRB 40
#define PERM_N (MAXRB * BM)

typedef __bf16 bf16x8 __attribute__((ext_vector_type(8)));
typedef float f32x4 __attribute__((ext_vector_type(4)));
typedef unsigned short u16x4v __attribute__((ext_vector_type(4)));
typedef unsigned short u16x8v __attribute__((ext_vector_type(8)));

#define H_CNT 0
#define H_FIL 8
#define H_OFF 16
#define H_NRB 24
#define H_BLK 32

static __device__ __forceinline__ unsigned short f2bf(float f) {
  return __builtin_bit_cast(unsigned short, (__bf16)f);
}
static __device__ __forceinline__ float bf2f(unsigned short s) {
  return __builtin_bit_cast(float, (unsigned)s << 16);
}
static __device__ __forceinline__ void gload16(const void* g, void* l) {
  __builtin_amdgcn_global_load_lds(
      (const __attribute__((address_space(1))) unsigned int*)g,
      (__attribute__((address_space(3))) unsigned int*)l, 16, 0, 0);
}

// ---------------- routing: one block, 1024 threads ---------------------------
__global__ __launch_bounds__(1024) void routing(const int* __restrict__ organ,
                                                int* __restrict__ hdr,
                                                int* __restrict__ perm) {
  __shared__ int cnt[EE], fil[EE], off[EE];
  const int tid = threadIdx.x;
  if (tid < EE) { cnt[tid] = 0; fil[tid] = 0; }
  __syncthreads();
#pragma unroll
  for (int i = 0; i < 4; ++i) atomicAdd(&cnt[organ[tid + (i << 10)]], 1);
#pragma unroll
  for (int i = 0; i < 5; ++i) perm[tid + (i << 10)] = -1;
  __syncthreads();
  if (tid == 0) {
    int acc = 0;
    for (int e = 0; e < EE; ++e) {
      off[e] = acc;
      hdr[H_OFF + e] = acc;
      hdr[H_CNT + e] = cnt[e];
      int nb = (cnt[e] + BM - 1) >> 7;
      int rb0 = acc >> 7;
      for (int i = 0; i < nb; ++i) hdr[H_BLK + rb0 + i] = e;
      acc += nb << 7;
    }
    hdr[H_NRB] = acc >> 7;
  }
  __syncthreads();
#pragma unroll
  for (int i = 0; i < 4; ++i) {
    int b = tid + (i << 10);
    int e = organ[b];
    int slot = off[e] + atomicAdd(&fil[e], 1);
    perm[slot] = b;
  }
}

// ---------------- a_build: 4 rows per block ----------------------------------
__global__ __launch_bounds__(256) void k_A(
    const float* __restrict__ vis, const float* __restrict__ txt,
    const int* __restrict__ hdr, const int* __restrict__ perm,
    unsigned short* __restrict__ Abuf) {
  const int bx = blockIdx.x;
  const int nr = hdr[H_NRB] << 7;
  const int tid = threadIdx.x;
  const int c = tid << 3;
  const float* srcbase = (c < DV) ? vis : txt;
  const int cc = (c < DV) ? c : c - DV;
#pragma unroll
  for (int p = 0; p < 4; ++p) {
    int r = (bx << 2) + p;
    if (r >= nr) return;
    int smp = perm[r];
    u16x8v v;
    if (smp >= 0) {
      const float* src = srcbase + (size_t)smp * 1024 + cc;
      float4 a = *(const float4*)src, b = *(const float4*)(src + 4);
      v[0] = f2bf(a.x); v[1] = f2bf(a.y); v[2] = f2bf(a.z); v[3] = f2bf(a.w);
      v[4] = f2bf(b.x); v[5] = f2bf(b.y); v[6] = f2bf(b.z); v[7] = f2bf(b.w);
    } else {
#pragma unroll
      for (int i = 0; i < 8; ++i) v[i] = 0;
    }
    *(u16x8v*)&Abuf[(size_t)r * DD + c] = v;
  }
}

static __device__ __forceinline__ void copy_body(
    int bx, const float4* __restrict__ v, const float4* __restrict__ t,
    float4* __restrict__ ov, float4* __restrict__ ot) {
  const int n4 = B_N * DV / 4;
  for (int i = bx * 256 + (int)threadIdx.x; i < n4; i += 1024 * 256) {
    ov[i] = v[i];
    ot[i] = t[i];
  }
}

// ---------------- GEMM core ---------------------------------------------------
// LDS (shorts): A0 @0, A1 @4096, B0 @8192, B1 @12288 (32 KiB)
// A rows [128][32] with 16B-chunk swizzle c ^= (row>>1)&3 (src-side pre-swizzle)
// B rows [n][32k] with 8B-slot swizzle s ^= (n^(n>>3))&7
// VMEM issue order per phase PINNED: [2x gload_lds A] sched_barrier [4x B].
// k0 arguments are ELEMENT offsets (tile << 5).
template <int KDIM, int NST>
static __device__ __forceinline__ void gemm_core(
    const unsigned short* __restrict__ Aseg,  // [128][KDIM] bf16 row-major
    const float* __restrict__ Bglob,          // [KDIM][NST] fp32 (col offset applied)
    unsigned short* smem, f32x4 (&acc)[4][4]) {
  const int tid = threadIdx.x;
  const int lane = tid & 63;
  const int wr = ((tid >> 6) >> 1) << 6, wc = ((tid >> 6) & 1) << 6;
  const int lr = lane & 15;
  const int arow = tid >> 2;
  const int kq_src = (((tid & 3) ^ ((arow >> 1) & 3)) << 3);  // swizzled src chunk
  const int wbase = (tid & 192) << 3;
  const int bn4 = (tid & 31) << 2;   // B: 4 consecutive n
  const int bk4 = (tid >> 5) << 2;   // B: 4 consecutive k
  constexpr int NT = KDIM / 32;

  float4 bvA[4], bvB[4];

  auto issueA = [&](int buf, int k0) {
    gload16(Aseg + (size_t)arow * KDIM + k0 + kq_src, smem + (buf << 12) + wbase);
    gload16(Aseg + (size_t)(64 + arow) * KDIM + k0 + kq_src,
            smem + (buf << 12) + 2048 + wbase);
  };
  auto issueB = [&](float4 (&bv)[4], int k0) {
    const float* p = Bglob + (size_t)(k0 + bk4) * NST + bn4;
#pragma unroll
    for (int i = 0; i < 4; ++i) bv[i] = *(const float4*)(p + (size_t)i * NST);
  };
  auto writeB = [&](int buf, float4 (&bv)[4]) {
    const float* f0 = (const float*)&bv[0];
    const float* f1 = (const float*)&bv[1];
    const float* f2 = (const float*)&bv[2];
    const float* f3 = (const float*)&bv[3];
#pragma unroll
    for (int j = 0; j < 4; ++j) {
      const int n = bn4 + j;
      const int s3 = (n ^ (n >> 3)) & 7;
      u16x4v w;
      w[0] = f2bf(f0[j]); w[1] = f2bf(f1[j]);
      w[2] = f2bf(f2[j]); w[3] = f2bf(f3[j]);
      *(u16x4v*)(smem + 8192 + (buf << 12) + (n << 5) + ((((bk4 >> 2)) ^ s3) << 2)) = w;
    }
  };
  auto compute = [&](int buf) {
    bf16x8 af[4], bfr[4];
#pragma unroll
    for (int m = 0; m < 4; ++m) {
      const int r = wr + m * 16 + lr;
      const int cs = ((lane >> 4) ^ ((r >> 1) & 3)) << 3;
      af[m] = *(const bf16x8*)&smem[(buf << 12) + r * 32 + cs];
    }
#pragma unroll
    for (int n = 0; n < 4; ++n) {
      const int fr = wc + n * 16 + lr;
      const int s3 = (fr ^ (fr >> 3)) & 7;
      const unsigned short* row = smem + 8192 + (buf << 12) + (fr << 5);
      const int g = (lane >> 4) << 1;
      union { unsigned long long q[2]; bf16x8 v; } u;
      u.q[0] = *(const unsigned long long*)(row + ((g ^ s3) << 2));
      u.q[1] = *(const unsigned long long*)(row + (((g + 1) ^ s3) << 2));
      bfr[n] = u.v;
    }
#pragma unroll
    for (int m = 0; m < 4; ++m)
#pragma unroll
      for (int n = 0; n < 4; ++n)
        acc[m][n] = __builtin_amdgcn_mfma_f32_16x16x32_bf16(af[m], bfr[n], acc[m][n], 0, 0, 0);
  };

  // prologue: tile0 B -> LDS, tile0 A -> LDS, tile1 B -> regs
  issueB(bvA, 0);
  writeB(0, bvA);                       // compiler auto-waits bvA loads
  issueA(0, 0);
  __builtin_amdgcn_sched_barrier(0);    // pin: A gloads older than bvB loads
  issueB(bvB, 1 << 5);
  asm volatile("s_waitcnt vmcnt(4) lgkmcnt(0)" ::: "memory");
  __builtin_amdgcn_s_barrier();

  int t = 0;
  for (; t + 2 < NT; t += 2) {
    // tile t from buf0
    issueA(1, (t + 1) << 5);
    __builtin_amdgcn_sched_barrier(0);  // pin: A older than next B prefetch
    issueB(bvA, (t + 2) << 5);
    compute(0);
    writeB(1, bvB);
    asm volatile("s_waitcnt vmcnt(4) lgkmcnt(0)" ::: "memory");
    __builtin_amdgcn_s_barrier();
    // tile t+1 from buf1
    issueA(0, (t + 2) << 5);
    __builtin_amdgcn_sched_barrier(0);
    issueB(bvB, (t + 3) << 5);
    compute(1);
    writeB(0, bvA);
    asm volatile("s_waitcnt vmcnt(4) lgkmcnt(0)" ::: "memory");
    __builtin_amdgcn_s_barrier();
  }
  // t == NT-2: buf0 holds tile NT-2, bvB holds B(NT-1)
  issueA(1, (NT - 1) << 5);
  compute(0);
  writeB(1, bvB);
  asm volatile("s_waitcnt vmcnt(0) lgkmcnt(0)" ::: "memory");
  __builtin_amdgcn_s_barrier();
  compute(1);
}

// ---------------- layer 1 (both heads) + copy_vt tail ------------------------
#define G_L1 (MAXRB * 16)   // 640
__global__ __launch_bounds__(256) void k_L1(
    const unsigned short* __restrict__ Abuf, const float* __restrict__ W1i,
    const float* __restrict__ W1g, const float* __restrict__ b1i,
    const float* __restrict__ b1g, const int* __restrict__ hdr,
    unsigned short* __restrict__ H1, unsigned short* __restrict__ H2,
    const float4* __restrict__ vis4, const float4* __restrict__ txt4,
    float4* __restrict__ ov, float4* __restrict__ ot) {
  __shared__ __align__(16) unsigned short smem[16384];
  int bx = blockIdx.x;
  if (bx >= G_L1) { copy_body(bx - G_L1, vis4, txt4, ov, ot); return; }
  const int id = (bx & 7) * (G_L1 >> 3) + (bx >> 3);  // XCD swizzle (640%8==0)
  const int rb = id % MAXRB;
  if (rb >= hdr[H_NRB]) return;
  const int sub = id / MAXRB, head = sub >> 3, cb = (sub & 7) << 7;
  const int e = hdr[H_BLK + rb];
  const float* Bglob = (head ? W1g : W1i) + (size_t)e * DD * HH + cb;
  const float* bias = (head ? b1g : b1i) + e * HH;
  unsigned short* Hout = head ? H2 : H1;
  const int tid = threadIdx.x;
  const int lane = tid & 63, wave = tid >> 6;
  const int wr = (wave >> 1) << 6, wc = (wave & 1) << 6;
  const int lr = lane & 15;

  f32x4 acc[4][4];
#pragma unroll
  for (int m = 0; m < 4; ++m)
#pragma unroll
    for (int n = 0; n < 4; ++n) acc[m][n] = (f32x4){0.f, 0.f, 0.f, 0.f};

  gemm_core<DD, HH>(Abuf + (size_t)rb * BM * DD, Bglob, smem, acc);
  __syncthreads();

  const int r0l = wr + ((lane >> 4) << 2);
#pragma unroll
  for (int n = 0; n < 4; ++n) {
    const int col = wc + n * 16 + lr;
    const float bv = bias[cb + col];
#pragma unroll
    for (int m = 0; m < 4; ++m)
#pragma unroll
      for (int v = 0; v < 4; ++v) {
        int row = r0l + m * 16 + v;
        float x = acc[m][n][v] + bv;
        x = x > 0.f ? x : 0.f;
        smem[((row << 7) + col) ^ ((row & 7) << 3)] = f2bf(x);
      }
  }
  __syncthreads();
#pragma unroll
  for (int c = 0; c < 8; ++c) {
    int q = c * 256 + tid;
    int row = q >> 4, ch = q & 15;
    int off = ((row << 7) + (ch << 3)) ^ ((row & 7) << 3);
    u16x8v val = *(const u16x8v*)&smem[off];
    *(u16x8v*)&Hout[(size_t)(rb * BM + row) * HH + cb + (ch << 3)] = val;
  }
}

// ---------------- immune dot -------------------------------------------------
static __device__ __forceinline__ void immune_body(
    int bx, const int* __restrict__ hdr, const int* __restrict__ perm,
    const unsigned short* __restrict__ H1, const float* __restrict__ W2,
    const float* __restrict__ b2, float* __restrict__ out) {
  const int nrb = hdr[H_NRB];
  const int r = bx * 4 + (threadIdx.x >> 6);
  if (r >= nrb * BM) return;
  const int b = perm[r];
  if (b < 0) return;
  const int e = hdr[H_BLK + (r >> 7)];
  const int lane = threadIdx.x & 63;
  const unsigned short* h = H1 + (size_t)r * HH + lane * 16;
  const float* w = W2 + (size_t)e * HH + lane * 16;
  float s = 0.f;
#pragma unroll
  for (int i = 0; i < 16; ++i) s += bf2f(h[i]) * w[i];
#pragma unroll
  for (int off = 32; off >= 1; off >>= 1) s += __shfl_xor(s, off, 64);
  if (lane == 0) out[b] = s + b2[e];
}

// ---------------- layer 2 (gene) ∥ immune ------------------------------------
#define G_L2 (MAXRB * 32)   // 1280
__global__ __launch_bounds__(256) void k_L2(
    const unsigned short* __restrict__ H2buf, const float* __restrict__ W2g,
    const float* __restrict__ b2g, const int* __restrict__ hdr,
    const int* __restrict__ perm, float* __restrict__ outg,
    const unsigned short* __restrict__ H1, const float* __restrict__ W2i,
    const float* __restrict__ b2i, float* __restrict__ outi) {
  __shared__ __align__(16) unsigned short smem[16384];
  int bx = blockIdx.x;
  if (bx >= G_L2) {
    immune_body(bx - G_L2, hdr, perm, H1, W2i, b2i, outi);
    return;
  }
  const int id = (bx & 7) * (G_L2 >> 3) + (bx >> 3);  // XCD swizzle (1280%8==0)
  const int rb = id % MAXRB;
  if (rb >= hdr[H_NRB]) return;
  const int cb = (id / MAXRB) << 7;
  const int e = hdr[H_BLK + rb];
  const float* Bglob = W2g + (size_t)e * HH * GG + cb;
  const int tid = threadIdx.x;
  const int lane = tid & 63, wave = tid >> 6;
  const int wr = (wave >> 1) << 6, wc = (wave & 1) << 6;
  const int lr = lane & 15;

  f32x4 acc[4][4];
#pragma unroll
  for (int m = 0; m < 4; ++m)
#pragma unroll
    for (int n = 0; n < 4; ++n) acc[m][n] = (f32x4){0.f, 0.f, 0.f, 0.f};

  gemm_core<HH, GG>(H2buf + (size_t)rb * BM * HH, Bglob, smem, acc);
  __syncthreads();

  const int r0l = wr + ((lane >> 4) << 2);
#pragma unroll
  for (int n = 0; n < 4; ++n) {
    const int col = wc + n * 16 + lr;
    const float bv = b2g[e * GG + cb + col];
#pragma unroll
    for (int m = 0; m < 4; ++m)
#pragma unroll
      for (int v = 0; v < 4; ++v) {
        int row = r0l + m * 16 + v;
        smem[((row << 7) + col) ^ ((row & 7) << 3)] = f2bf(acc[m][n][v] + bv);
      }
  }
  __syncthreads();
#pragma unroll
  for (int c = 0; c < 8; ++c) {
    int q = c * 256 + tid;
    int row = q >> 4, ch = q & 15;
    int sm = perm[rb * BM + row];
    if (sm < 0) continue;
    int off = ((row << 7) + (ch << 3)) ^ ((row & 7) << 3);
    u16x8v val = *(const u16x8v*)&smem[off];
    float4 f0, f1;
    f0.x = bf2f(val[0]); f0.y = bf2f(val[1]); f0.z = bf2f(val[2]); f0.w = bf2f(val[3]);
    f1.x = bf2f(val[4]); f1.y = bf2f(val[5]); f1.z = bf2f(val[6]); f1.w = bf2f(val[7]);
    float* dst = outg + (size_t)sm * GG + cb + (ch << 3);
    *(float4*)dst = f0;
    *(float4*)(dst + 4) = f1;
  }
}

// ================= host ======================================================
extern "C" void kernel_launch(void* const* d_in, const int* in_sizes, int n_in,
                              void* d_out, int out_size, void* d_ws, size_t ws_size,
                              hipStream_t stream) {
  (void)in_sizes; (void)n_in; (void)out_size; (void)ws_size;
  const float* vis = (const float*)d_in[0];
  const float* txt = (const float*)d_in[1];
  const float* W1i = (const float*)d_in[2];
  const float* b1i = (const float*)d_in[3];
  const float* W2i = (const float*)d_in[4];
  const float* b2i = (const float*)d_in[5];
  const float* W1g = (const float*)d_in[6];
  const float* b1g = (const float*)d_in[7];
  const float* W2g = (const float*)d_in[8];
  const float* b2g = (const float*)d_in[9];
  const int* organ = (const int*)d_in[10];

  float* out_imm = (float*)d_out;
  float* out_gene = out_imm + B_N;
  float* out_vis = out_gene + (size_t)B_N * GG;
  float* out_txt = out_vis + (size_t)B_N * DV;

  int* hdr = (int*)d_ws;
  int* perm = hdr + 128;

  const size_t OFF_ABUF = 32768;
  const size_t OFF_H1 = OFF_ABUF + (size_t)PERM_N * DD * 2;
  const size_t OFF_H2 = OFF_H1 + (size_t)PERM_N * HH * 2;
  unsigned short* Abuf = (unsigned short*)((char*)d_ws + OFF_ABUF);
  unsigned short* H1 = (unsigned short*)((char*)d_ws + OFF_H1);
  unsigned short* H2 = (unsigned short*)((char*)d_ws + OFF_H2);

  routing<<<1, 1024, 0, stream>>>(organ, hdr, perm);
  k_A<<<PERM_N / 4, 256, 0, stream>>>(vis, txt, hdr, perm, Abuf);
  k_L1<<<G_L1 + 1024, 256, 0, stream>>>(Abuf, W1i, W1g, b1i, b1g, hdr, H1, H2,
                                        (const float4*)vis, (const float4*)txt,
                                        (float4*)out_vis, (float4*)out_txt);
  k_L2<<<G_L2 + PERM_N / 4, 256, 0, stream>>>(H2, W2g, b2g, hdr, perm, out_gene,
                                              H1, W2i, b2i, out_imm);
}

// Round 8
// 250.266 us; speedup vs baseline: 1.1308x; 1.0351x over previous
//
#include <hip/hip_runtime.h>

// MultiHeadModel routed MoE (E=8), round 8.
// = round 7 with a 3-deep A prefetch pipeline (4 LDS A-buffers, 48 KiB LDS):
// per phase t: issue A(t+3) -> issue B(t+2) regs -> compute(t) -> writeB(t+1).
// The compiler's own vmcnt wait for the B(t+1) regs (in-order retirement)
// guarantees A(t+1)/A(t+2) are in LDS -- no hand-counted vmcnt anywhere.
//   routing -> k_A(a_build) -> k_L1(GEMM both heads + copy_vt) -> k_L2(GEMM + immune)

#define B_N 4096
#define DV  1024
#define DD  2048
#define HH  1024
#define GG  4096
#define EE  8
#define BM  128
#define MAXRB 40
#define PERM_N (MAXRB * BM)

typedef __bf16 bf16x8 __attribute__((ext_vector_type(8)));
typedef float f32x4 __attribute__((ext_vector_type(4)));
typedef unsigned short u16x4v __attribute__((ext_vector_type(4)));
typedef unsigned short u16x8v __attribute__((ext_vector_type(8)));

#define H_CNT 0
#define H_FIL 8
#define H_OFF 16
#define H_NRB 24
#define H_BLK 32

static __device__ __forceinline__ unsigned short f2bf(float f) {
  return __builtin_bit_cast(unsigned short, (__bf16)f);
}
static __device__ __forceinline__ float bf2f(unsigned short s) {
  return __builtin_bit_cast(float, (unsigned)s << 16);
}
static __device__ __forceinline__ void gload16(const void* g, void* l) {
  __builtin_amdgcn_global_load_lds(
      (const __attribute__((address_space(1))) unsigned int*)g,
      (__attribute__((address_space(3))) unsigned int*)l, 16, 0, 0);
}

// ---------------- routing: one block, 1024 threads ---------------------------
__global__ __launch_bounds__(1024) void routing(const int* __restrict__ organ,
                                                int* __restrict__ hdr,
                                                int* __restrict__ perm) {
  __shared__ int cnt[EE], fil[EE], off[EE];
  const int tid = threadIdx.x;
  if (tid < EE) { cnt[tid] = 0; fil[tid] = 0; }
  __syncthreads();
#pragma unroll
  for (int i = 0; i < 4; ++i) atomicAdd(&cnt[organ[tid + (i << 10)]], 1);
#pragma unroll
  for (int i = 0; i < 5; ++i) perm[tid + (i << 10)] = -1;
  __syncthreads();
  if (tid == 0) {
    int acc = 0;
    for (int e = 0; e < EE; ++e) {
      off[e] = acc;
      hdr[H_OFF + e] = acc;
      hdr[H_CNT + e] = cnt[e];
      int nb = (cnt[e] + BM - 1) >> 7;
      int rb0 = acc >> 7;
      for (int i = 0; i < nb; ++i) hdr[H_BLK + rb0 + i] = e;
      acc += nb << 7;
    }
    hdr[H_NRB] = acc >> 7;
  }
  __syncthreads();
#pragma unroll
  for (int i = 0; i < 4; ++i) {
    int b = tid + (i << 10);
    int e = organ[b];
    int slot = off[e] + atomicAdd(&fil[e], 1);
    perm[slot] = b;
  }
}

// ---------------- a_build: 4 rows per block ----------------------------------
__global__ __launch_bounds__(256) void k_A(
    const float* __restrict__ vis, const float* __restrict__ txt,
    const int* __restrict__ hdr, const int* __restrict__ perm,
    unsigned short* __restrict__ Abuf) {
  const int bx = blockIdx.x;
  const int nr = hdr[H_NRB] << 7;
  const int tid = threadIdx.x;
  const int c = tid << 3;
  const float* srcbase = (c < DV) ? vis : txt;
  const int cc = (c < DV) ? c : c - DV;
#pragma unroll
  for (int p = 0; p < 4; ++p) {
    int r = (bx << 2) + p;
    if (r >= nr) return;
    int smp = perm[r];
    u16x8v v;
    if (smp >= 0) {
      const float* src = srcbase + (size_t)smp * 1024 + cc;
      float4 a = *(const float4*)src, b = *(const float4*)(src + 4);
      v[0] = f2bf(a.x); v[1] = f2bf(a.y); v[2] = f2bf(a.z); v[3] = f2bf(a.w);
      v[4] = f2bf(b.x); v[5] = f2bf(b.y); v[6] = f2bf(b.z); v[7] = f2bf(b.w);
    } else {
#pragma unroll
      for (int i = 0; i < 8; ++i) v[i] = 0;
    }
    *(u16x8v*)&Abuf[(size_t)r * DD + c] = v;
  }
}

static __device__ __forceinline__ void copy_body(
    int bx, const float4* __restrict__ v, const float4* __restrict__ t,
    float4* __restrict__ ov, float4* __restrict__ ot) {
  const int n4 = B_N * DV / 4;
  for (int i = bx * 256 + (int)threadIdx.x; i < n4; i += 1024 * 256) {
    ov[i] = v[i];
    ot[i] = t[i];
  }
}

// ---------------- GEMM core ---------------------------------------------------
// LDS (shorts): A bufs 4 x 4096 @ 0; B bufs 2 x 4096 @ 16384. 48 KiB total.
// A rows [128][32] with 16B-chunk swizzle c ^= (row>>1)&3 (src-side pre-swizzle)
// B rows [n][32k] with 8B-slot swizzle s ^= (n^(n>>3))&7
// Phase t issue order PINNED: [A(t+3) gloads] SB [B(t+2) reg loads] SB
//   [compute(t) + writeB(t+1)] lgkmcnt(0) s_barrier SB.
template <int KDIM, int NST>
static __device__ __forceinline__ void gemm_core(
    const unsigned short* __restrict__ Aseg,  // [128][KDIM] bf16 row-major
    const float* __restrict__ Bglob,          // [KDIM][NST] fp32 (col offset applied)
    unsigned short* smem, f32x4 (&acc)[4][4]) {
  const int tid = threadIdx.x;
  const int lane = tid & 63;
  const int wr = ((tid >> 6) >> 1) << 6, wc = ((tid >> 6) & 1) << 6;
  const int lr = lane & 15;
  const int arow = tid >> 2;
  const int kq_src = (((tid & 3) ^ ((arow >> 1) & 3)) << 3);  // swizzled src chunk
  const int wbase = (tid & 192) << 3;
  const int bn4 = (tid & 31) << 2;   // B: 4 consecutive n
  const int bk4 = (tid >> 5) << 2;   // B: 4 consecutive k
  constexpr int NT = KDIM / 32;

  float4 bvE[4], bvO[4];

  auto issueA = [&](int buf, int k0) {
    unsigned short* d = smem + (buf << 12) + wbase;
    gload16(Aseg + (size_t)arow * KDIM + k0 + kq_src, d);
    gload16(Aseg + (size_t)(64 + arow) * KDIM + k0 + kq_src, d + 2048);
  };
  auto issueB = [&](float4 (&bv)[4], int k0) {
    const float* p = Bglob + (size_t)(k0 + bk4) * NST + bn4;
#pragma unroll
    for (int i = 0; i < 4; ++i) bv[i] = *(const float4*)(p + (size_t)i * NST);
  };
  auto writeB = [&](int buf, float4 (&bv)[4]) {
    const float* f0 = (const float*)&bv[0];
    const float* f1 = (const float*)&bv[1];
    const float* f2 = (const float*)&bv[2];
    const float* f3 = (const float*)&bv[3];
#pragma unroll
    for (int j = 0; j < 4; ++j) {
      const int n = bn4 + j;
      const int s3 = (n ^ (n >> 3)) & 7;
      u16x4v w;
      w[0] = f2bf(f0[j]); w[1] = f2bf(f1[j]);
      w[2] = f2bf(f2[j]); w[3] = f2bf(f3[j]);
      *(u16x4v*)(smem + 16384 + (buf << 12) + (n << 5) + ((((bk4 >> 2)) ^ s3) << 2)) = w;
    }
  };
  auto compute = [&](int ab, int bb) {
    bf16x8 af[4], bfr[4];
#pragma unroll
    for (int m = 0; m < 4; ++m) {
      const int r = wr + m * 16 + lr;
      const int cs = ((lane >> 4) ^ ((r >> 1) & 3)) << 3;
      af[m] = *(const bf16x8*)&smem[(ab << 12) + r * 32 + cs];
    }
#pragma unroll
    for (int n = 0; n < 4; ++n) {
      const int fr = wc + n * 16 + lr;
      const int s3 = (fr ^ (fr >> 3)) & 7;
      const unsigned short* row = smem + 16384 + (bb << 12) + (fr << 5);
      const int g = (lane >> 4) << 1;
      union { unsigned long long q[2]; bf16x8 v; } u;
      u.q[0] = *(const unsigned long long*)(row + ((g ^ s3) << 2));
      u.q[1] = *(const unsigned long long*)(row + (((g + 1) ^ s3) << 2));
      bfr[n] = u.v;
    }
#pragma unroll
    for (int m = 0; m < 4; ++m)
#pragma unroll
      for (int n = 0; n < 4; ++n)
        acc[m][n] = __builtin_amdgcn_mfma_f32_16x16x32_bf16(af[m], bfr[n], acc[m][n], 0, 0, 0);
  };

  auto phase = [&](int t, float4 (&bvIss)[4], float4 (&bvWr)[4]) {
    if (t + 3 < NT) issueA((t + 3) & 3, (t + 3) << 5);
    __builtin_amdgcn_sched_barrier(0);
    if (t + 2 < NT) issueB(bvIss, (t + 2) << 5);
    __builtin_amdgcn_sched_barrier(0);
    compute(t & 3, t & 1);
    if (t + 1 < NT) writeB((t + 1) & 1, bvWr);  // implicit vmcnt wait covers A(t+1),A(t+2)
    asm volatile("s_waitcnt lgkmcnt(0)" ::: "memory");
    __builtin_amdgcn_s_barrier();
    __builtin_amdgcn_sched_barrier(0);
  };

  // prologue: A0,B0 -> LDS; A1,A2 gloads in flight; B1 regs in flight.
  issueA(0, 0);
  __builtin_amdgcn_sched_barrier(0);
  issueB(bvE, 0);
  writeB(0, bvE);                     // waits bvE -> retires A0
  issueA(1, 1 << 5);
  __builtin_amdgcn_sched_barrier(0);
  issueA(2, 2 << 5);
  __builtin_amdgcn_sched_barrier(0);
  issueB(bvO, 1 << 5);
  asm volatile("s_waitcnt lgkmcnt(0)" ::: "memory");
  __builtin_amdgcn_s_barrier();
  __builtin_amdgcn_sched_barrier(0);

  for (int t = 0; t < NT; t += 2) {
    phase(t, bvE, bvO);       // issues B(t+2)->bvE, writes B(t+1) from bvO
    phase(t + 1, bvO, bvE);   // issues B(t+3)->bvO, writes B(t+2) from bvE
  }
}

// ---------------- layer 1 (both heads) + copy_vt tail ------------------------
#define G_L1 (MAXRB * 16)   // 640
__global__ __launch_bounds__(256) void k_L1(
    const unsigned short* __restrict__ Abuf, const float* __restrict__ W1i,
    const float* __restrict__ W1g, const float* __restrict__ b1i,
    const float* __restrict__ b1g, const int* __restrict__ hdr,
    unsigned short* __restrict__ H1, unsigned short* __restrict__ H2,
    const float4* __restrict__ vis4, const float4* __restrict__ txt4,
    float4* __restrict__ ov, float4* __restrict__ ot) {
  __shared__ __align__(16) unsigned short smem[24576];
  int bx = blockIdx.x;
  if (bx >= G_L1) { copy_body(bx - G_L1, vis4, txt4, ov, ot); return; }
  const int id = (bx & 7) * (G_L1 >> 3) + (bx >> 3);  // XCD swizzle (640%8==0)
  const int rb = id % MAXRB;
  if (rb >= hdr[H_NRB]) return;
  const int sub = id / MAXRB, head = sub >> 3, cb = (sub & 7) << 7;
  const int e = hdr[H_BLK + rb];
  const float* Bglob = (head ? W1g : W1i) + (size_t)e * DD * HH + cb;
  const float* bias = (head ? b1g : b1i) + e * HH;
  unsigned short* Hout = head ? H2 : H1;
  const int tid = threadIdx.x;
  const int lane = tid & 63, wave = tid >> 6;
  const int wr = (wave >> 1) << 6, wc = (wave & 1) << 6;
  const int lr = lane & 15;

  f32x4 acc[4][4];
#pragma unroll
  for (int m = 0; m < 4; ++m)
#pragma unroll
    for (int n = 0; n < 4; ++n) acc[m][n] = (f32x4){0.f, 0.f, 0.f, 0.f};

  gemm_core<DD, HH>(Abuf + (size_t)rb * BM * DD, Bglob, smem, acc);
  __syncthreads();

  const int r0l = wr + ((lane >> 4) << 2);
#pragma unroll
  for (int n = 0; n < 4; ++n) {
    const int col = wc + n * 16 + lr;
    const float bv = bias[cb + col];
#pragma unroll
    for (int m = 0; m < 4; ++m)
#pragma unroll
      for (int v = 0; v < 4; ++v) {
        int row = r0l + m * 16 + v;
        float x = acc[m][n][v] + bv;
        x = x > 0.f ? x : 0.f;
        smem[((row << 7) + col) ^ ((row & 7) << 3)] = f2bf(x);
      }
  }
  __syncthreads();
#pragma unroll
  for (int c = 0; c < 8; ++c) {
    int q = c * 256 + tid;
    int row = q >> 4, ch = q & 15;
    int off = ((row << 7) + (ch << 3)) ^ ((row & 7) << 3);
    u16x8v val = *(const u16x8v*)&smem[off];
    *(u16x8v*)&Hout[(size_t)(rb * BM + row) * HH + cb + (ch << 3)] = val;
  }
}

// ---------------- immune dot -------------------------------------------------
static __device__ __forceinline__ void immune_body(
    int bx, const int* __restrict__ hdr, const int* __restrict__ perm,
    const unsigned short* __restrict__ H1, const float* __restrict__ W2,
    const float* __restrict__ b2, float* __restrict__ out) {
  const int nrb = hdr[H_NRB];
  const int r = bx * 4 + (threadIdx.x >> 6);
  if (r >= nrb * BM) return;
  const int b = perm[r];
  if (b < 0) return;
  const int e = hdr[H_BLK + (r >> 7)];
  const int lane = threadIdx.x & 63;
  const unsigned short* h = H1 + (size_t)r * HH + lane * 16;
  const float* w = W2 + (size_t)e * HH + lane * 16;
  float s = 0.f;
#pragma unroll
  for (int i = 0; i < 16; ++i) s += bf2f(h[i]) * w[i];
#pragma unroll
  for (int off = 32; off >= 1; off >>= 1) s += __shfl_xor(s, off, 64);
  if (lane == 0) out[b] = s + b2[e];
}

// ---------------- layer 2 (gene) ∥ immune ------------------------------------
#define G_L2 (MAXRB * 32)   // 1280
__global__ __launch_bounds__(256) void k_L2(
    const unsigned short* __restrict__ H2buf, const float* __restrict__ W2g,
    const float* __restrict__ b2g, const int* __restrict__ hdr,
    const int* __restrict__ perm, float* __restrict__ outg,
    const unsigned short* __restrict__ H1, const float* __restrict__ W2i,
    const float* __restrict__ b2i, float* __restrict__ outi) {
  __shared__ __align__(16) unsigned short smem[24576];
  int bx = blockIdx.x;
  if (bx >= G_L2) {
    immune_body(bx - G_L2, hdr, perm, H1, W2i, b2i, outi);
    return;
  }
  const int id = (bx & 7) * (G_L2 >> 3) + (bx >> 3);  // XCD swizzle (1280%8==0)
  const int rb = id % MAXRB;
  if (rb >= hdr[H_NRB]) return;
  const int cb = (id / MAXRB) << 7;
  const int e = hdr[H_BLK + rb];
  const float* Bglob = W2g + (size_t)e * HH * GG + cb;
  const int tid = threadIdx.x;
  const int lane = tid & 63, wave = tid >> 6;
  const int wr = (wave >> 1) << 6, wc = (wave & 1) << 6;
  const int lr = lane & 15;

  f32x4 acc[4][4];
#pragma unroll
  for (int m = 0; m < 4; ++m)
#pragma unroll
    for (int n = 0; n < 4; ++n) acc[m][n] = (f32x4){0.f, 0.f, 0.f, 0.f};

  gemm_core<HH, GG>(H2buf + (size_t)rb * BM * HH, Bglob, smem, acc);
  __syncthreads();

  const int r0l = wr + ((lane >> 4) << 2);
#pragma unroll
  for (int n = 0; n < 4; ++n) {
    const int col = wc + n * 16 + lr;
    const float bv = b2g[e * GG + cb + col];
#pragma unroll
    for (int m = 0; m < 4; ++m)
#pragma unroll
      for (int v = 0; v < 4; ++v) {
        int row = r0l + m * 16 + v;
        smem[((row << 7) + col) ^ ((row & 7) << 3)] = f2bf(acc[m][n][v] + bv);
      }
  }
  __syncthreads();
#pragma unroll
  for (int c = 0; c < 8; ++c) {
    int q = c * 256 + tid;
    int row = q >> 4, ch = q & 15;
    int sm = perm[rb * BM + row];
    if (sm < 0) continue;
    int off = ((row << 7) + (ch << 3)) ^ ((row & 7) << 3);
    u16x8v val = *(const u16x8v*)&smem[off];
    float4 f0, f1;
    f0.x = bf2f(val[0]); f0.y = bf2f(val[1]); f0.z = bf2f(val[2]); f0.w = bf2f(val[3]);
    f1.x = bf2f(val[4]); f1.y = bf2f(val[5]); f1.z = bf2f(val[6]); f1.w = bf2f(val[7]);
    float* dst = outg + (size_t)sm * GG + cb + (ch << 3);
    *(float4*)dst = f0;
    *(float4*)(dst + 4) = f1;
  }
}

// ================= host ======================================================
extern "C" void kernel_launch(void* const* d_in, const int* in_sizes, int n_in,
                              void* d_out, int out_size, void* d_ws, size_t ws_size,
                              hipStream_t stream) {
  (void)in_sizes; (void)n_in; (void)out_size; (void)ws_size;
  const float* vis = (const float*)d_in[0];
  const float* txt = (const float*)d_in[1];
  const float* W1i = (const float*)d_in[2];
  const float* b1i = (const float*)d_in[3];
  const float* W2i = (const float*)d_in[4];
  const float* b2i = (const float*)d_in[5];
  const float* W1g = (const float*)d_in[6];
  const float* b1g = (const float*)d_in[7];
  const float* W2g = (const float*)d_in[8];
  const float* b2g = (const float*)d_in[9];
  const int* organ = (const int*)d_in[10];

  float* out_imm = (float*)d_out;
  float* out_gene = out_imm + B_N;
  float* out_vis = out_gene + (size_t)B_N * GG;
  float* out_txt = out_vis + (size_t)B_N * DV;

  int* hdr = (int*)d_ws;
  int* perm = hdr + 128;

  const size_t OFF_ABUF = 32768;
  const size_t OFF_H1 = OFF_ABUF + (size_t)PERM_N * DD * 2;
  const size_t OFF_H2 = OFF_H1 + (size_t)PERM_N * HH * 2;
  unsigned short* Abuf = (unsigned short*)((char*)d_ws + OFF_ABUF);
  unsigned short* H1 = (unsigned short*)((char*)d_ws + OFF_H1);
  unsigned short* H2 = (unsigned short*)((char*)d_ws + OFF_H2);

  routing<<<1, 1024, 0, stream>>>(organ, hdr, perm);
  k_A<<<PERM_N / 4, 256, 0, stream>>>(vis, txt, hdr, perm, Abuf);
  k_L1<<<G_L1 + 1024, 256, 0, stream>>>(Abuf, W1i, W1g, b1i, b1g, hdr, H1, H2,
                                        (const float4*)vis, (const float4*)txt,
                                        (float4*)out_vis, (float4*)out_txt);
  k_L2<<<G_L2 + PERM_N / 4, 256, 0, stream>>>(H2, W2g, b2g, hdr, perm, out_gene,
                                              H1, W2i, b2i, out_imm);
}